// Round 5
// baseline (549.497 us; speedup 1.0000x reference)
//
#include <hip/hip_runtime.h>

#define N_USERS  200000
#define N_ITEMS  100000
#define N_TOTAL  300000
#define EMB_DIM  64
#define N_EDGES  4000000
#define N_LAYERS 3

// generic scan: 1024 elements per scan block
#define SCAN_CHUNK 1024

// radix partition: 512-row buckets, 4096-edge chunks
#define B2_BITS 9
#define B2_ROWS (1 << B2_BITS)                                     // 512
#define NB2 ((N_TOTAL + B2_ROWS - 1) >> B2_BITS)                   // 586
#define CHUNK_E 4096
#define NBLK ((N_EDGES + CHUNK_E - 1) / CHUNK_E)                   // 977
#define NFLAT (NB2 * NBLK)                                         // 572,522
#define NSB_FLAT ((NFLAT + SCAN_CHUNK - 1) / SCAN_CHUNK)           // 560

// edge packing: (local_row[9b] << 19) | dst[19b];  N_TOTAL < 2^19
#define DST_BITS 19
#define DST_MASK ((1 << DST_BITS) - 1)

// part2 LDS staging capacity (ints). Bucket size ~Poisson(6826), sd~83;
// 10240 is >40 sigma. Overflow -> 2-pass fallback (correctness preserved).
#define P2_CAP 10240

// gather: rows per wave (4 rounds of 4 quarter-rows)
#define GROWS 16

typedef float f32x2 __attribute__((ext_vector_type(2)));

// ---- bf16 helpers ----
__device__ __forceinline__ unsigned bfpack(float a, float b) {
    unsigned ua = __float_as_uint(a); ua = (ua + 0x7fffu + ((ua >> 16) & 1u)) >> 16;
    unsigned ub = __float_as_uint(b); ub = (ub + 0x7fffu + ((ub >> 16) & 1u)) >> 16;
    return ua | (ub << 16);
}
__device__ __forceinline__ float bflo(unsigned u) { return __uint_as_float(u << 16); }
__device__ __forceinline__ float bfhi(unsigned u) { return __uint_as_float(u & 0xffff0000u); }
__device__ __forceinline__ f32x2 bf2(unsigned u) {
    f32x2 t; t.x = bflo(u); t.y = bfhi(u); return t;   // candidates for v_pk_add_f32 fusion
}

// ---------------- 2-level scan (block-sum correction folded into consumers) ----
__global__ void scanA_g(const int* __restrict__ in, int* __restrict__ out,
                        int* __restrict__ bsums, int n) {
    __shared__ int lds[256];
    int t = threadIdx.x, b = blockIdx.x;
    int base = b * SCAN_CHUNK + t * 4;
    int v[4];
#pragma unroll
    for (int k = 0; k < 4; ++k)
        v[k] = (base + k < n) ? in[base + k] : 0;
    int s = v[0] + v[1] + v[2] + v[3];
    lds[t] = s;
    __syncthreads();
    for (int off = 1; off < 256; off <<= 1) {
        int x = (t >= off) ? lds[t - off] : 0;
        __syncthreads();
        lds[t] += x;
        __syncthreads();
    }
    int inc = lds[t];
    int exc = inc - s;
    if (t == 255) bsums[b] = inc;
    int run = exc;
#pragma unroll
    for (int k = 0; k < 4; ++k) {
        if (base + k < n) out[base + k] = run;
        run += v[k];
    }
}

// up to 1024 entries (2 per thread)
__global__ void scanB_g(int* __restrict__ bsums, int nb) {
    __shared__ int lds[512];
    int t = threadIdx.x;
    int v0 = (2 * t < nb) ? bsums[2 * t] : 0;
    int v1 = (2 * t + 1 < nb) ? bsums[2 * t + 1] : 0;
    int s = v0 + v1;
    lds[t] = s;
    __syncthreads();
    for (int o = 1; o < 512; o <<= 1) {
        int x = (t >= o) ? lds[t - o] : 0;
        __syncthreads();
        lds[t] += x;
        __syncthreads();
    }
    int exc = lds[t] - s;
    if (2 * t < nb) bsums[2 * t] = exc;
    if (2 * t + 1 < nb) bsums[2 * t + 1] = exc + v0;
}

// ---- partition phase A: per-(block,bucket) counts via LDS; int4 edge loads ----
__global__ __launch_bounds__(512) void partA_kernel(const int* __restrict__ src,
                                                    int* __restrict__ bcnt) {
    __shared__ int lcnt[NB2];
    int blk = blockIdx.x, t = threadIdx.x;
    for (int i = t; i < NB2; i += 512) lcnt[i] = 0;
    __syncthreads();
    int base = blk * CHUNK_E;
    int end = base + CHUNK_E; if (end > N_EDGES) end = N_EDGES;
    for (int e = base + 4 * t; e < end; e += 4 * 512) {
        int4 s4 = *(const int4*)(src + e);
        atomicAdd(&lcnt[s4.x >> B2_BITS], 1);
        atomicAdd(&lcnt[s4.y >> B2_BITS], 1);
        atomicAdd(&lcnt[s4.z >> B2_BITS], 1);
        atomicAdd(&lcnt[s4.w >> B2_BITS], 1);
    }
    __syncthreads();
    for (int i = t; i < NB2; i += 512)
        bcnt[(size_t)i * NBLK + blk] = lcnt[i];
}

// ---- partition phase C: write packed edges into block-private ranges ----
__global__ __launch_bounds__(512) void partC_kernel(const int* __restrict__ src,
                                                    const int* __restrict__ dst,
                                                    const int* __restrict__ boffs,
                                                    const int* __restrict__ bs2,
                                                    int* __restrict__ edgebuf) {
    __shared__ int lcur[NB2];
    int blk = blockIdx.x, t = threadIdx.x;
    for (int i = t; i < NB2; i += 512) {
        size_t f = (size_t)i * NBLK + blk;
        lcur[i] = boffs[f] + bs2[f >> 10];           // folded scanC
    }
    __syncthreads();
    int base = blk * CHUNK_E;
    int end = base + CHUNK_E; if (end > N_EDGES) end = N_EDGES;
    for (int e = base + 2 * t; e < end; e += 2 * 512) {
        int2 s2 = *(const int2*)(src + e);
        int2 d2 = *(const int2*)(dst + e);
        int pos0 = atomicAdd(&lcur[s2.x >> B2_BITS], 1);
        edgebuf[pos0] = ((s2.x & (B2_ROWS - 1)) << DST_BITS) | d2.x;
        int pos1 = atomicAdd(&lcur[s2.y >> B2_BITS], 1);
        edgebuf[pos1] = ((s2.y & (B2_ROWS - 1)) << DST_BITS) | d2.y;
    }
}

// ---- fused fine pass: per-bucket hist + scan -> offs/dinv, then scatter col ----
// Bucket edges staged in LDS (single global read); overflow -> 2-pass fallback.
__global__ __launch_bounds__(512) void part2_kernel(const int* __restrict__ boffs,
                                                    const int* __restrict__ bs2,
                                                    const int* __restrict__ edgebuf,
                                                    int* __restrict__ col,
                                                    int* __restrict__ offs,
                                                    float* __restrict__ dinv) {
    __shared__ int lhist[B2_ROWS];    // counts, then running write cursors
    __shared__ int lsums[512];
    __shared__ int lbuf[P2_CAP];
    int b = blockIdx.x;
    int base = b << B2_BITS;
    int nrows = N_TOTAL - base; if (nrows > B2_ROWS) nrows = B2_ROWS;
    int t = threadIdx.x;
    size_t f0 = (size_t)b * NBLK;
    int bstart = boffs[f0] + bs2[f0 >> 10];
    int eend;
    if (b + 1 < NB2) {
        size_t f1 = (size_t)(b + 1) * NBLK;
        eend = boffs[f1] + bs2[f1 >> 10];
    } else eend = N_EDGES;
    int cnt = eend - bstart;
    bool fits = (cnt <= P2_CAP);

    if (t < B2_ROWS) lhist[t] = 0;
    __syncthreads();
    // pass 1: per-row counts (and stage edges in LDS if they fit)
    if (fits) {
        for (int j = t; j < cnt; j += 512) {
            int e = edgebuf[bstart + j];
            lbuf[j] = e;
            atomicAdd(&lhist[e >> DST_BITS], 1);
        }
    } else {
        for (int j = bstart + t; j < eend; j += 512)
            atomicAdd(&lhist[edgebuf[j] >> DST_BITS], 1);
    }
    __syncthreads();
    // exclusive scan of 512 counts (1 per thread)
    int v = lhist[t];
    lsums[t] = v;
    __syncthreads();
    for (int o = 1; o < 512; o <<= 1) {
        int x = (t >= o) ? lsums[t - o] : 0;
        __syncthreads();
        lsums[t] += x;
        __syncthreads();
    }
    int o0 = bstart + lsums[t] - v;         // exclusive
    if (t < nrows) {
        offs[base + t] = o0;
        dinv[base + t] = rsqrtf((float)v + 1e-8f);
    }
    if (b == NB2 - 1 && t == 0) offs[N_TOTAL] = N_EDGES;
    // reuse lhist as write cursors
    lhist[t] = o0;
    __syncthreads();
    // pass 2: scatter dst into row-sorted col
    if (fits) {
        for (int j = t; j < cnt; j += 512) {
            int e = lbuf[j];
            int pos = atomicAdd(&lhist[e >> DST_BITS], 1);
            col[pos] = e & DST_MASK;
        }
    } else {
        for (int j = bstart + t; j < eend; j += 512) {
            int e = edgebuf[j];
            int pos = atomicAdd(&lhist[e >> DST_BITS], 1);
            col[pos] = e & DST_MASK;
        }
    }
}

// ---- g0 = dinv ⊙ concat(user_w, item_w), bf16x2 packed; row N_TOTAL = zeros ----
__global__ void convert_kernel(const float4* __restrict__ uw4,
                               const float4* __restrict__ iw4,
                               const float* __restrict__ dinv,
                               uint2* __restrict__ g0) {
    int i = blockIdx.x * blockDim.x + threadIdx.x;
    const int n = (N_TOTAL + 1) * 16;
    if (i < n) {
        int row = i >> 4;
        if (row >= N_TOTAL) {
            g0[i] = make_uint2(0u, 0u);      // dummy zero row
        } else {
            float4 x = (row < N_USERS) ? uw4[i] : iw4[i - N_USERS * 16];
            float di = dinv[row];
            g0[i] = make_uint2(bfpack(di * x.x, di * x.y),
                               bfpack(di * x.z, di * x.w));
        }
    }
}

// ---------------- gather SpMM on pre-scaled g tables ----------------
// h_next[row] = dinv[row] * sum_{edges} g_prev[col];  g_next = dinv * h_next.
// Reduction-free layout: each 16-lane quarter owns ONE row; lane r covers dims
// 4r..4r+3 (uint2 = 8B, 128B per quarter-gather). A wave handles GROWS=16 rows
// in 4 rounds of 4 rows; the 4 rows of a round share one wave-uniform edge loop
// bounded by kmax=max(degrees), sentinel-padded (dummy gathers hit the
// L1-resident zero row at index N_TOTAL). No cross-lane reduction; epilogue
// stores run on all 64 lanes. Next round's col window is prefetched.
// MODE 0: out = x + h.  MODE 1: out += h.  MODE 2: out = (out+h)/4, no g_next.
template <int MODE>
__global__ __launch_bounds__(256) void gather_kernel(
        const int* __restrict__ offs,
        const int* __restrict__ col,
        const float* __restrict__ dinv,
        const unsigned* __restrict__ gprev,
        unsigned* __restrict__ gnext,
        float4* __restrict__ out4,
        const float4* __restrict__ uw4,
        const float4* __restrict__ iw4) {
    int wid  = blockIdx.x * 4 + (threadIdx.x >> 6);
    int base = wid * GROWS;
    int lane = threadIdx.x & 63;
    int q    = lane >> 4;          // quarter = own row within round
    int r    = lane & 15;          // dims 4r..4r+3
    if (base < N_TOTAL) {
        // lanes 0..16 hold offs[base..base+16]; lane r holds dinv[base+r] (x4 repl)
        int   off_l = offs[base + (lane < GROWS + 1 ? lane : GROWS)];
        float dv_l  = dinv[base + r];
        // stage round-0 window-0 col indices for own quarter-row
        int s_l = __shfl(off_l, q);
        int e_l = __shfl(off_l, q + 1);
        int myc_cur = (r < e_l - s_l) ? col[s_l + r] : N_TOTAL;
#pragma unroll
        for (int j = 0; j < GROWS / 4; ++j) {
            // wave-uniform degrees of this round's 4 rows
            int o0 = __builtin_amdgcn_readlane(off_l, 4 * j);
            int o1 = __builtin_amdgcn_readlane(off_l, 4 * j + 1);
            int o2 = __builtin_amdgcn_readlane(off_l, 4 * j + 2);
            int o3 = __builtin_amdgcn_readlane(off_l, 4 * j + 3);
            int o4 = __builtin_amdgcn_readlane(off_l, 4 * j + 4);
            int kmax = max(max(o1 - o0, o2 - o1), max(o3 - o2, o4 - o3));
            // per-lane window params for own quarter-row
            int s_lane = __shfl(off_l, 4 * j + q);
            int n_lane = __shfl(off_l, 4 * j + q + 1) - s_lane;
            // prefetch next round's window-0 col indices
            int myc_next = N_TOTAL;
            if (j + 1 < GROWS / 4) {
                int sn = __shfl(off_l, 4 * (j + 1) + q);
                int en = __shfl(off_l, 4 * (j + 1) + q + 1);
                myc_next = (r < en - sn) ? col[sn + r] : N_TOTAL;
            }
            f32x2 acc01 = {0.f, 0.f};
            f32x2 acc23 = {0.f, 0.f};
            int myc = myc_cur;
            for (int w0 = 0; w0 < kmax; w0 += 16) {
                int kw = kmax - w0; if (kw > 16) kw = 16;
                for (int k = 0; k < kw; k += 4) {
                    int bl = (q << 4) + k;
                    int c0 = __shfl(myc, bl);
                    int c1 = __shfl(myc, bl + 1);
                    int c2 = __shfl(myc, bl + 2);
                    int c3 = __shfl(myc, bl + 3);
                    uint2 u0 = *(const uint2*)(gprev + ((size_t)(unsigned)c0 << 5) + 2 * r);
                    uint2 u1 = *(const uint2*)(gprev + ((size_t)(unsigned)c1 << 5) + 2 * r);
                    uint2 u2 = *(const uint2*)(gprev + ((size_t)(unsigned)c2 << 5) + 2 * r);
                    uint2 u3 = *(const uint2*)(gprev + ((size_t)(unsigned)c3 << 5) + 2 * r);
                    acc01 += bf2(u0.x); acc23 += bf2(u0.y);
                    acc01 += bf2(u1.x); acc23 += bf2(u1.y);
                    acc01 += bf2(u2.x); acc23 += bf2(u2.y);
                    acc01 += bf2(u3.x); acc23 += bf2(u3.y);
                }
                // reload next 16-edge window for own quarter-row (rare: deg>16)
                if (w0 + 16 < kmax) {
                    int o = w0 + 16;
                    myc = (o + r < n_lane) ? col[s_lane + o + r] : N_TOTAL;
                }
            }
            // epilogue: all 64 lanes store (4 rows per wave)
            float di = __shfl(dv_l, 4 * j + q);
            int row = base + 4 * j + q;
            float h0 = di * acc01.x, h1 = di * acc01.y;
            float h2 = di * acc23.x, h3 = di * acc23.y;
            int p = row * 16 + r;
            if (MODE == 0) {
                float4 x = (row < N_USERS) ? uw4[p] : iw4[p - N_USERS * 16];
                ((uint2*)gnext)[p] = make_uint2(bfpack(di * h0, di * h1),
                                                bfpack(di * h2, di * h3));
                out4[p] = make_float4(x.x + h0, x.y + h1, x.z + h2, x.w + h3);
            } else if (MODE == 1) {
                float4 o = out4[p];
                ((uint2*)gnext)[p] = make_uint2(bfpack(di * h0, di * h1),
                                                bfpack(di * h2, di * h3));
                out4[p] = make_float4(o.x + h0, o.y + h1, o.z + h2, o.w + h3);
            } else {
                float4 o = out4[p];
                out4[p] = make_float4((o.x + h0) * 0.25f, (o.y + h1) * 0.25f,
                                      (o.z + h2) * 0.25f, (o.w + h3) * 0.25f);
            }
            myc_cur = myc_next;
        }
    }
    // maintain the zero row of the table the NEXT kernel gathers from
    if (MODE != 2) {
        if (blockIdx.x == 0 && threadIdx.x < 32)
            gnext[N_TOTAL * 32 + threadIdx.x] = 0u;
    }
}

extern "C" void kernel_launch(void* const* d_in, const int* in_sizes, int n_in,
                              void* d_out, int out_size, void* d_ws, size_t ws_size,
                              hipStream_t stream) {
    const float* user_w = (const float*)d_in[0];
    const float* item_w = (const float*)d_in[1];
    const int*   src    = (const int*)d_in[2];
    const int*   dst    = (const int*)d_in[3];
    float* out = (float*)d_out;
    (void)in_sizes; (void)n_in; (void)out_size; (void)ws_size;

    char* ws = (char*)d_ws;
    size_t off = 0;
    auto alloc = [&](size_t bytes) {
        char* p = ws + off;
        off = (off + bytes + 255) & ~(size_t)255;
        return p;
    };
    int*      offs   = (int*)     alloc((size_t)(N_TOTAL + 1) * 4);
    int*      bcnt   = (int*)     alloc((size_t)NFLAT * 4);              // 2.3 MB
    int*      boffs  = (int*)     alloc((size_t)NFLAT * 4);              // 2.3 MB
    int*      bs2    = (int*)     alloc((size_t)NSB_FLAT * 4);
    int*      col    = (int*)     alloc((size_t)N_EDGES * 4);            // 16 MB
    int*      edgebuf= (int*)     alloc((size_t)N_EDGES * 4);            // 16 MB (packed)
    float*    dinv   = (float*)   alloc((size_t)N_TOTAL * 4);
    unsigned* g0     = (unsigned*)alloc((size_t)(N_TOTAL + 1) * 32 * 4); // 38.4 MB
    unsigned* g_a    = (unsigned*)alloc((size_t)(N_TOTAL + 1) * 32 * 4); // 38.4 MB
    unsigned* g_b    = (unsigned*)alloc((size_t)(N_TOTAL + 1) * 32 * 4); // 38.4 MB

    const int B = 256;
    const int nWaves = (N_TOTAL + GROWS - 1) / GROWS;     // 18750
    const int gatherGrid = (nWaves + 3) / 4;              // 4688

    // radix partition into 512-row buckets (block-private write ranges)
    partA_kernel<<<NBLK, 512, 0, stream>>>(src, bcnt);
    scanA_g<<<NSB_FLAT, B, 0, stream>>>(bcnt, boffs, bs2, NFLAT);
    scanB_g<<<1, 512, 0, stream>>>(bs2, NSB_FLAT);
    partC_kernel<<<NBLK, 512, 0, stream>>>(src, dst, boffs, bs2, edgebuf);
    // fused: per-bucket hist + scan -> offs, dinv; scatter col (LDS-staged)
    part2_kernel<<<NB2, 512, 0, stream>>>(boffs, bs2, edgebuf, col, offs, dinv);

    // g0 = dinv * x (bf16), plus zero dummy row
    convert_kernel<<<((N_TOTAL + 1) * 16 + B - 1) / B, B, 0, stream>>>(
        (const float4*)user_w, (const float4*)item_w, dinv, (uint2*)g0);

    const float4* uw4 = (const float4*)user_w;
    const float4* iw4 = (const float4*)item_w;
    float4* out4 = (float4*)out;
    gather_kernel<0><<<gatherGrid, B, 0, stream>>>(offs, col, dinv, g0,  g_a, out4, uw4, iw4);
    gather_kernel<1><<<gatherGrid, B, 0, stream>>>(offs, col, dinv, g_a, g_b, out4, uw4, iw4);
    gather_kernel<2><<<gatherGrid, B, 0, stream>>>(offs, col, dinv, g_b, nullptr, out4, uw4, iw4);
}

// Round 6
// 538.008 us; speedup vs baseline: 1.0214x; 1.0214x over previous
//
#include <hip/hip_runtime.h>

#define N_USERS  200000
#define N_ITEMS  100000
#define N_TOTAL  300000
#define EMB_DIM  64
#define N_EDGES  4000000
#define N_LAYERS 3

// radix partition: 512-row buckets, 8192-edge chunks, fixed-capacity regions
#define B2_BITS 9
#define B2_ROWS (1 << B2_BITS)                                     // 512
#define NB2 ((N_TOTAL + B2_ROWS - 1) >> B2_BITS)                   // 586
#define CHUNK_E 8192
#define NBLK ((N_EDGES + CHUNK_E - 1) / CHUNK_E)                   // 489
#define BCAP_BITS 13
#define BCAP (1 << BCAP_BITS)                                      // 8192/bucket (+16 sigma)

// edge packing: (local_row[9b] << 19) | dst[19b];  N_TOTAL < 2^19
#define DST_BITS 19
#define DST_MASK ((1 << DST_BITS) - 1)

// gather: rows per wave
#define GR 4

typedef float f32x2 __attribute__((ext_vector_type(2)));

// ---- bf16 helpers ----
__device__ __forceinline__ unsigned bfpack(float a, float b) {
    unsigned ua = __float_as_uint(a); ua = (ua + 0x7fffu + ((ua >> 16) & 1u)) >> 16;
    unsigned ub = __float_as_uint(b); ub = (ub + 0x7fffu + ((ub >> 16) & 1u)) >> 16;
    return ua | (ub << 16);
}
__device__ __forceinline__ float bflo(unsigned u) { return __uint_as_float(u << 16); }
__device__ __forceinline__ float bfhi(unsigned u) { return __uint_as_float(u & 0xffff0000u); }
__device__ __forceinline__ f32x2 bf2(unsigned u) {
    f32x2 t; t.x = bflo(u); t.y = bfhi(u); return t;   // candidates for v_pk_add_f32 fusion
}

// ---- fused partition: count (LDS) -> reserve (global atomic) -> scatter ----
// Each bucket owns a fixed 8192-slot region of edgebuf; gcur[b] ends up
// holding the bucket's edge count. No global offset scan needed.
__global__ __launch_bounds__(512) void part1_kernel(const int* __restrict__ src,
                                                    const int* __restrict__ dst,
                                                    int* __restrict__ gcur,
                                                    int* __restrict__ edgebuf) {
    __shared__ int lcnt[NB2];
    __shared__ int lcur[NB2];
    __shared__ int ssrc[CHUNK_E];
    int blk = blockIdx.x, t = threadIdx.x;
    for (int i = t; i < NB2; i += 512) lcnt[i] = 0;
    __syncthreads();
    int base = blk * CHUNK_E;
    int end = base + CHUNK_E; if (end > N_EDGES) end = N_EDGES;
    for (int e = base + 4 * t; e < end; e += 4 * 512) {
        int4 s4 = *(const int4*)(src + e);
        *(int4*)(ssrc + (e - base)) = s4;
        atomicAdd(&lcnt[s4.x >> B2_BITS], 1);
        atomicAdd(&lcnt[s4.y >> B2_BITS], 1);
        atomicAdd(&lcnt[s4.z >> B2_BITS], 1);
        atomicAdd(&lcnt[s4.w >> B2_BITS], 1);
    }
    __syncthreads();
    for (int i = t; i < NB2; i += 512) {
        int c = lcnt[i];
        int b0 = c ? atomicAdd(&gcur[i], c) : 0;
        lcur[i] = (i << BCAP_BITS) + b0;             // absolute write cursor
    }
    __syncthreads();
    for (int e = base + 4 * t; e < end; e += 4 * 512) {
        int4 d4 = *(const int4*)(dst + e);
        int j = e - base;
        int s0 = ssrc[j], s1 = ssrc[j + 1], s2 = ssrc[j + 2], s3 = ssrc[j + 3];
        int p0 = atomicAdd(&lcur[s0 >> B2_BITS], 1);
        edgebuf[p0] = ((s0 & (B2_ROWS - 1)) << DST_BITS) | d4.x;
        int p1 = atomicAdd(&lcur[s1 >> B2_BITS], 1);
        edgebuf[p1] = ((s1 & (B2_ROWS - 1)) << DST_BITS) | d4.y;
        int p2 = atomicAdd(&lcur[s2 >> B2_BITS], 1);
        edgebuf[p2] = ((s2 & (B2_ROWS - 1)) << DST_BITS) | d4.z;
        int p3 = atomicAdd(&lcur[s3 >> B2_BITS], 1);
        edgebuf[p3] = ((s3 & (B2_ROWS - 1)) << DST_BITS) | d4.w;
    }
}

// ---- tiny scan over 586 bucket totals -> CSR bucket bases; zero sentinel row ----
__global__ void scanT_kernel(const int* __restrict__ gcur, int* __restrict__ bbase,
                             unsigned* __restrict__ g0) {
    __shared__ int lds[512];
    int t = threadIdx.x;
    int v0 = (2 * t < NB2) ? gcur[2 * t] : 0;
    int v1 = (2 * t + 1 < NB2) ? gcur[2 * t + 1] : 0;
    int s = v0 + v1;
    lds[t] = s;
    __syncthreads();
    for (int o = 1; o < 512; o <<= 1) {
        int x = (t >= o) ? lds[t - o] : 0;
        __syncthreads();
        lds[t] += x;
        __syncthreads();
    }
    int exc = lds[t] - s;
    if (2 * t < NB2) bbase[2 * t] = exc;
    if (2 * t + 1 < NB2) bbase[2 * t + 1] = exc + v0;
    if (t == 511) bbase[NB2] = lds[511];
    if (t < 32) g0[(size_t)N_TOTAL * 32 + t] = 0u;   // zero dummy row
}

// ---- fused fine pass: per-bucket hist+scan -> offs/dinv, scatter col, write g0 ----
__global__ __launch_bounds__(512) void part2_kernel(const int* __restrict__ gcur,
                                                    const int* __restrict__ bbase,
                                                    const int* __restrict__ edgebuf,
                                                    int* __restrict__ col,
                                                    int* __restrict__ offs,
                                                    float* __restrict__ dinv,
                                                    const float4* __restrict__ uw4,
                                                    const float4* __restrict__ iw4,
                                                    uint2* __restrict__ g0) {
    __shared__ int lhist[B2_ROWS];    // counts, then running write cursors
    __shared__ int lsums[512];        // scan workspace, then dinv stash
    __shared__ int lbuf[BCAP];        // staged bucket edges (single global read)
    int b = blockIdx.x;
    int base = b << B2_BITS;
    int nrows = N_TOTAL - base; if (nrows > B2_ROWS) nrows = B2_ROWS;
    int t = threadIdx.x;
    int cnt    = gcur[b];
    int bstart = bbase[b];
    int ebase  = b << BCAP_BITS;

    lhist[t] = 0;
    __syncthreads();
    // pass 1: stage + per-row counts
    for (int j = t; j < cnt; j += 512) {
        int e = edgebuf[ebase + j];
        lbuf[j] = e;
        atomicAdd(&lhist[e >> DST_BITS], 1);
    }
    __syncthreads();
    // exclusive scan of 512 counts
    int v = lhist[t];
    lsums[t] = v;
    __syncthreads();
    for (int o = 1; o < 512; o <<= 1) {
        int x = (t >= o) ? lsums[t - o] : 0;
        __syncthreads();
        lsums[t] += x;
        __syncthreads();
    }
    int o0 = bstart + lsums[t] - v;         // exclusive row offset
    float dv = rsqrtf((float)v + 1e-8f);
    if (t < nrows) {
        offs[base + t] = o0;
        dinv[base + t] = dv;
    }
    if (b == NB2 - 1 && t == 0) offs[N_TOTAL] = N_EDGES;
    __syncthreads();
    lhist[t] = o0;                           // reuse as write cursors
    lsums[t] = __float_as_int(dv);           // stash dinv for g0 writer
    __syncthreads();
    // pass 2: scatter dst into row-sorted col (from LDS)
    for (int j = t; j < cnt; j += 512) {
        int e = lbuf[j];
        int pos = atomicAdd(&lhist[e >> DST_BITS], 1);
        col[pos] = e & DST_MASK;
    }
    // fused convert: g0[row] = dinv[row] * x[row] (bf16x2 packed)
    int np = nrows << 4;
    for (int p = t; p < np; p += 512) {
        int rl = p >> 4, rr = p & 15;
        int row = base + rl;
        float di = __int_as_float(lsums[rl]);
        float4 x = (row < N_USERS) ? uw4[row * 16 + rr]
                                   : iw4[(row - N_USERS) * 16 + rr];
        g0[row * 16 + rr] = make_uint2(bfpack(di * x.x, di * x.y),
                                       bfpack(di * x.z, di * x.w));
    }
}

// ---------------- gather SpMM on pre-scaled g tables (R4 variant) ----------------
// h_next[row] = dinv[row] * sum_{edges} g_prev[col];  g_next = dinv * h_next.
// Each wave handles GR=4 rows; one coalesced load fetches the GR+1 offsets
// (readlane -> SGPRs) and GR dinv values; row i+1's col-index window is
// prefetched while row i's gathers are in flight (cross-row pipelining).
// 4 edge streams (16-lane quarters); lane r of quarter q covers dims 4r..4r+3
// via one dwordx2 load; 16 edges per inner iter => 4 gathers in flight.
// Out-of-range shfl slots hold the zero-row index N_TOTAL (no bounds logic).
// MODE 0: out = x + h.  MODE 1: out += h.  MODE 2: out = (out+h)/4, no g_next.
template <int MODE>
__global__ __launch_bounds__(256) void gather_kernel(
        const int* __restrict__ offs,
        const int* __restrict__ col,
        const float* __restrict__ dinv,
        const unsigned* __restrict__ gprev,
        unsigned* __restrict__ gnext,
        float4* __restrict__ out4,
        const float4* __restrict__ uw4,
        const float4* __restrict__ iw4) {
    int wid  = blockIdx.x * 4 + (threadIdx.x >> 6);
    int base_row = wid * GR;
    int lane = threadIdx.x & 63;
    int q    = lane >> 4;          // quarter = edge stream
    int r    = lane & 15;          // dims 4r..4r+3
    // coalesced: lanes 0..GR hold offs[base_row..base_row+GR]; 0..GR-1 hold dinv
    int li = lane < GR ? lane : GR;
    int off_l = offs[base_row + li];
    float dv  = dinv[base_row + (lane < GR ? lane : GR - 1)];

    // prefetch row 0's first col window
    int s0 = __builtin_amdgcn_readlane(off_l, 0);
    int e0 = __builtin_amdgcn_readlane(off_l, 1);
    int myc_cur = (lane < e0 - s0) ? col[s0 + lane] : N_TOTAL;

#pragma unroll
    for (int i = 0; i < GR; ++i) {
        int start = __builtin_amdgcn_readlane(off_l, i);
        int end   = __builtin_amdgcn_readlane(off_l, i + 1);
        // prefetch next row's first window before draining this row's gathers
        int myc_next = N_TOTAL;
        if (i + 1 < GR) {
            int sn = __builtin_amdgcn_readlane(off_l, i + 1);
            int en = __builtin_amdgcn_readlane(off_l, i + 2);
            myc_next = (lane < en - sn) ? col[sn + lane] : N_TOTAL;
        }
        f32x2 acc01 = {0.f, 0.f};
        f32x2 acc23 = {0.f, 0.f};
        int n = end - start; if (n > 64) n = 64;
        for (int k0 = 0; k0 < n; k0 += 16) {
            int c0 = __shfl(myc_cur, k0 + q);
            int c1 = __shfl(myc_cur, k0 + 4 + q);
            int c2 = __shfl(myc_cur, k0 + 8 + q);
            int c3 = __shfl(myc_cur, k0 + 12 + q);
            uint2 u0 = *(const uint2*)(gprev + ((size_t)(unsigned)c0 << 5) + 2 * r);
            uint2 u1 = *(const uint2*)(gprev + ((size_t)(unsigned)c1 << 5) + 2 * r);
            uint2 u2 = *(const uint2*)(gprev + ((size_t)(unsigned)c2 << 5) + 2 * r);
            uint2 u3 = *(const uint2*)(gprev + ((size_t)(unsigned)c3 << 5) + 2 * r);
            acc01 += bf2(u0.x); acc23 += bf2(u0.y);
            acc01 += bf2(u1.x); acc23 += bf2(u1.y);
            acc01 += bf2(u2.x); acc23 += bf2(u2.y);
            acc01 += bf2(u3.x); acc23 += bf2(u3.y);
        }
        // rare: rows with degree > 64
        for (int cb = start + 64; cb < end; cb += 64) {
            int rem = end - cb;
            int nn = rem > 64 ? 64 : rem;
            int myc = (lane < rem) ? col[cb + lane] : N_TOTAL;
            for (int k0 = 0; k0 < nn; k0 += 16) {
                int c0 = __shfl(myc, k0 + q);
                int c1 = __shfl(myc, k0 + 4 + q);
                int c2 = __shfl(myc, k0 + 8 + q);
                int c3 = __shfl(myc, k0 + 12 + q);
                uint2 u0 = *(const uint2*)(gprev + ((size_t)(unsigned)c0 << 5) + 2 * r);
                uint2 u1 = *(const uint2*)(gprev + ((size_t)(unsigned)c1 << 5) + 2 * r);
                uint2 u2 = *(const uint2*)(gprev + ((size_t)(unsigned)c2 << 5) + 2 * r);
                uint2 u3 = *(const uint2*)(gprev + ((size_t)(unsigned)c3 << 5) + 2 * r);
                acc01 += bf2(u0.x); acc23 += bf2(u0.y);
                acc01 += bf2(u1.x); acc23 += bf2(u1.y);
                acc01 += bf2(u2.x); acc23 += bf2(u2.y);
                acc01 += bf2(u3.x); acc23 += bf2(u3.y);
            }
        }
        float a0 = acc01.x, a1 = acc01.y, a2 = acc23.x, a3 = acc23.y;
        a0 += __shfl_xor(a0, 16);
        a1 += __shfl_xor(a1, 16);
        a2 += __shfl_xor(a2, 16);
        a3 += __shfl_xor(a3, 16);
        a0 += __shfl_xor(a0, 32);
        a1 += __shfl_xor(a1, 32);
        a2 += __shfl_xor(a2, 32);
        a3 += __shfl_xor(a3, 32);
        float di = __shfl(dv, i);
        if (lane < 16) {
            int row = base_row + i;
            float h0 = di * a0, h1 = di * a1, h2 = di * a2, h3 = di * a3;
            int p = row * 16 + r;
            if (MODE == 0) {
                float4 x = (row < N_USERS) ? uw4[p] : iw4[p - N_USERS * 16];
                ((uint2*)gnext)[p] = make_uint2(bfpack(di * h0, di * h1),
                                                bfpack(di * h2, di * h3));
                out4[p] = make_float4(x.x + h0, x.y + h1, x.z + h2, x.w + h3);
            } else if (MODE == 1) {
                float4 o = out4[p];
                ((uint2*)gnext)[p] = make_uint2(bfpack(di * h0, di * h1),
                                                bfpack(di * h2, di * h3));
                out4[p] = make_float4(o.x + h0, o.y + h1, o.z + h2, o.w + h3);
            } else {
                float4 o = out4[p];
                out4[p] = make_float4((o.x + h0) * 0.25f, (o.y + h1) * 0.25f,
                                      (o.z + h2) * 0.25f, (o.w + h3) * 0.25f);
            }
        }
        myc_cur = myc_next;
    }
    // maintain the zero row of the table the NEXT kernel gathers from
    if (MODE != 2) {
        if (blockIdx.x == 0 && threadIdx.x < 32)
            gnext[(size_t)N_TOTAL * 32 + threadIdx.x] = 0u;
    }
}

extern "C" void kernel_launch(void* const* d_in, const int* in_sizes, int n_in,
                              void* d_out, int out_size, void* d_ws, size_t ws_size,
                              hipStream_t stream) {
    const float* user_w = (const float*)d_in[0];
    const float* item_w = (const float*)d_in[1];
    const int*   src    = (const int*)d_in[2];
    const int*   dst    = (const int*)d_in[3];
    float* out = (float*)d_out;
    (void)in_sizes; (void)n_in; (void)out_size; (void)ws_size;

    char* ws = (char*)d_ws;
    size_t off = 0;
    auto alloc = [&](size_t bytes) {
        char* p = ws + off;
        off = (off + bytes + 255) & ~(size_t)255;
        return p;
    };
    int*      gcur   = (int*)     alloc((size_t)NB2 * 4);
    int*      bbase  = (int*)     alloc((size_t)(NB2 + 1) * 4);
    int*      offs   = (int*)     alloc((size_t)(N_TOTAL + 1) * 4);
    float*    dinv   = (float*)   alloc((size_t)N_TOTAL * 4);
    int*      col    = (int*)     alloc((size_t)N_EDGES * 4);            // 16 MB
    int*      edgebuf= (int*)     alloc((size_t)NB2 * BCAP * 4);         // 19.2 MB
    unsigned* g0     = (unsigned*)alloc((size_t)(N_TOTAL + 1) * 32 * 4); // 38.4 MB
    unsigned* g_a    = (unsigned*)alloc((size_t)(N_TOTAL + 1) * 32 * 4); // 38.4 MB
    unsigned* g_b    = (unsigned*)alloc((size_t)(N_TOTAL + 1) * 32 * 4); // 38.4 MB

    const int B = 256;
    const int gatherGrid = N_TOTAL / (4 * GR);   // 18750

    const float4* uw4 = (const float4*)user_w;
    const float4* iw4 = (const float4*)item_w;
    float4* out4 = (float4*)out;

    // fused partition into fixed-capacity bucket regions
    hipMemsetAsync(gcur, 0, (size_t)NB2 * 4, stream);
    part1_kernel<<<NBLK, 512, 0, stream>>>(src, dst, gcur, edgebuf);
    // bucket bases (586-entry scan) + g0 sentinel row
    scanT_kernel<<<1, 512, 0, stream>>>(gcur, bbase, g0);
    // per-bucket hist+scan -> offs/dinv, scatter col, fused g0 convert
    part2_kernel<<<NB2, 512, 0, stream>>>(gcur, bbase, edgebuf, col, offs, dinv,
                                          uw4, iw4, (uint2*)g0);

    gather_kernel<0><<<gatherGrid, B, 0, stream>>>(offs, col, dinv, g0,  g_a, out4, uw4, iw4);
    gather_kernel<1><<<gatherGrid, B, 0, stream>>>(offs, col, dinv, g_a, g_b, out4, uw4, iw4);
    gather_kernel<2><<<gatherGrid, B, 0, stream>>>(offs, col, dinv, g_b, nullptr, out4, uw4, iw4);
}